// Round 2
// baseline (139.949 us; speedup 1.0000x reference)
//
#include <hip/hip_runtime.h>
#include <math.h>

// For each edge m: p[k] = dot(z[src][k*32:(k+1)*32], z[trg][k*32:(k+1)*32]),
// out[m] = sigmoid(max_k p[k]).  One 64-lane wave per edge:
// lane loads float4 from each row (64*16B = 1024B = full 256-float row),
// 8-lane group = one capsule (32 floats), shfl_xor reduce.
//
// NOTE: harness converts integer inputs to int32 — edge_index arrives as
// const int* with in_sizes[1] = 2*M elements.

__global__ __launch_bounds__(256) void max_deco_kernel(
    const float* __restrict__ z,
    const int* __restrict__ ei,   // (2, M) int32
    float* __restrict__ out,
    int m_total)
{
    const int wave = blockIdx.x * (blockDim.x >> 6) + (threadIdx.x >> 6);
    const int lane = threadIdx.x & 63;
    if (wave >= m_total) return;

    const int i0 = ei[wave];            // src row
    const int i1 = ei[wave + m_total];  // trg row

    const float4* __restrict__ src = (const float4*)(z + (size_t)i0 * 256);
    const float4* __restrict__ trg = (const float4*)(z + (size_t)i1 * 256);

    float4 a = src[lane];
    float4 b = trg[lane];
    float d = a.x * b.x + a.y * b.y + a.z * b.z + a.w * b.w;

    // sum within the 8-lane capsule group (capsule = 32 contiguous floats)
    d += __shfl_xor(d, 1);
    d += __shfl_xor(d, 2);
    d += __shfl_xor(d, 4);

    // every lane now holds its capsule's dot; max across the 8 capsules
    d = fmaxf(d, __shfl_xor(d, 8));
    d = fmaxf(d, __shfl_xor(d, 16));
    d = fmaxf(d, __shfl_xor(d, 32));

    if (lane == 0) {
        out[wave] = 1.0f / (1.0f + __expf(-d));
    }
}

extern "C" void kernel_launch(void* const* d_in, const int* in_sizes, int n_in,
                              void* d_out, int out_size, void* d_ws, size_t ws_size,
                              hipStream_t stream) {
    const float* z = (const float*)d_in[0];
    const int* ei = (const int*)d_in[1];
    float* out = (float*)d_out;

    const int m_total = in_sizes[1] / 2;   // edge_index is (2, M)

    // 4 waves (edges) per 256-thread block
    const int edges_per_block = 256 / 64;
    const int grid = (m_total + edges_per_block - 1) / edges_per_block;

    max_deco_kernel<<<grid, 256, 0, stream>>>(z, ei, out, m_total);
}